// Round 2
// baseline (587.241 us; speedup 1.0000x reference)
//
#include <hip/hip_runtime.h>

#define GAS __attribute__((address_space(1)))
#define LAS __attribute__((address_space(3)))

typedef __attribute__((ext_vector_type(8))) _Float16 half8;
typedef __attribute__((ext_vector_type(4))) float floatx4;
typedef __attribute__((ext_vector_type(4))) unsigned short ushort4v;

static constexpr int B_  = 16;
static constexpr int LQ  = 512;
static constexpr int LC  = 2048;
static constexpr int D_  = 1024;
static constexpr int DO  = 2048;   // output feature dim (concat)
static constexpr int MT  = 64;     // context rows per block

__device__ __forceinline__ void gl2lds16(const void* g, void* l) {
  __builtin_amdgcn_global_load_lds((const GAS unsigned int*)g,
                                   (LAS unsigned int*)l, 16, 0, 0);
}

__device__ __forceinline__ unsigned short f2h(float f) {
  return __builtin_bit_cast(unsigned short, (_Float16)f);   // v_cvt_f16_f32 RNE
}

// fp32 -> fp16 streaming convert (n4 = element count / 4)
__global__ void conv_kernel(const float* __restrict__ src,
                            unsigned short* __restrict__ dst, int n4) {
  int i = blockIdx.x * blockDim.x + threadIdx.x;
  const int stride = gridDim.x * blockDim.x;
  for (; i < n4; i += stride) {
    const float4 v = ((const float4*)src)[i];
    ushort4v h;
    h.x = f2h(v.x); h.y = f2h(v.y); h.z = f2h(v.z); h.w = f2h(v.w);
    ((ushort4v*)dst)[i] = h;
  }
}

// QT[b][d][q] = Qh[b][q][d]  (fp16 bits)
__global__ void qtransh_kernel(const unsigned short* __restrict__ qh,
                               unsigned short* __restrict__ qt) {
  __shared__ unsigned short t[32][33];
  const int b = blockIdx.z, d0 = blockIdx.x * 32, q0 = blockIdx.y * 32;
  const unsigned short* src = qh + (size_t)b * LQ * D_;
  unsigned short* dst = qt + (size_t)b * D_ * LQ;
  for (int i = threadIdx.y; i < 32; i += 8)
    t[i][threadIdx.x] = src[(size_t)(q0 + i) * D_ + d0 + threadIdx.x];
  __syncthreads();
  for (int i = threadIdx.y; i < 32; i += 8)
    dst[(size_t)(d0 + i) * LQ + q0 + threadIdx.x] = t[threadIdx.x][i];
}

__launch_bounds__(512, 4)
__global__ void attn_main(const unsigned short* __restrict__ qg,   // Qh fp16
                          const unsigned short* __restrict__ cg,   // Ch fp16
                          const unsigned short* __restrict__ qtg,  // QTh fp16
                          unsigned short* __restrict__ pg,         // P fp16 ws
                          const float* __restrict__ cf,            // C fp32
                          float* __restrict__ og) {                // out fp32
  // LDS: frag-major staging blocks (1 KiB each) + softmax reduction scratch
  __shared__ __align__(16) char smem[32 * 1024 + 4 * 1024 + 2048 + 256];
  char* Qbuf = smem;                           // 32 frag blocks (B operand)
  char* Cbuf = smem + 32768;                   // 4 frag blocks  (A operand)
  float* redf    = (float*)(smem + 36864);     // [8 waves][64 rows]
  float* rowstat = (float*)(smem + 38912);     // [64] rowmax, then rowinv

  const int tid  = threadIdx.x;
  const int wave = tid >> 6;
  const int lane = tid & 63;
  const int l15  = lane & 15;
  const int quad = lane >> 4;
  const int q8   = quad * 8;

  const int b    = blockIdx.x & 15;   // XCD-swizzle: batch b -> XCD b%8
  const int tile = blockIdx.x >> 4;
  const int c0   = tile * MT;

  const unsigned short* Q  = qg  + (size_t)b * LQ * D_;
  const unsigned short* C  = cg  + (size_t)b * LC * D_;
  const unsigned short* QT = qtg + (size_t)b * D_ * LQ;
  unsigned short*       P  = pg  + (size_t)b * LC * LQ;
  const float*          CF = cf  + (size_t)b * LC * D_;
  float*                O  = og  + (size_t)b * LC * DO;

  // ---- passthrough: out[:, :D] = context (fp32, float4 per lane) ----
  for (int i = tid; i < MT * (D_ / 4); i += 512) {
    const int r = i >> 8, ch = i & 255;
    ((float4*)(O + (size_t)(c0 + r) * DO))[ch] =
        ((const float4*)(CF + (size_t)(c0 + r) * D_))[ch];
  }

  floatx4 acc[4][4];
#pragma unroll
  for (int i = 0; i < 4; ++i)
#pragma unroll
    for (int j = 0; j < 4; ++j) acc[i][j] = floatx4{0.f, 0.f, 0.f, 0.f};

  // ================= Phase 1: S = C_tile (64xK) * Q^T (Kx512) ============
#pragma unroll 1
  for (int it = 0; it < 32; ++it) {
    const int k0 = it * 32;
#pragma unroll
    for (int j = 0; j < 5; ++j) {
      const int bb = wave + j * 8;          // wave-uniform
      if (bb < 36) {
        const unsigned short* g;
        char* l;
        if (bb < 32) {      // Q frag block: rows = q index
          g = Q + (size_t)(bb * 16 + l15) * D_ + k0 + q8;
          l = Qbuf + bb * 1024;
        } else {            // C frag block: rows = context rows
          const int mt = bb - 32;
          g = C + (size_t)(c0 + mt * 16 + l15) * D_ + k0 + q8;
          l = Cbuf + mt * 1024;
        }
        gl2lds16(g, l);
      }
    }
    __syncthreads();
    half8 af[4], bf[4];
#pragma unroll
    for (int mt = 0; mt < 4; ++mt)
      af[mt] = *(const half8*)(Cbuf + mt * 1024 + lane * 16);
#pragma unroll
    for (int nt = 0; nt < 4; ++nt)
      bf[nt] = *(const half8*)(Qbuf + (wave * 4 + nt) * 1024 + lane * 16);
#pragma unroll
    for (int mt = 0; mt < 4; ++mt)
#pragma unroll
      for (int nt = 0; nt < 4; ++nt)
        acc[mt][nt] = __builtin_amdgcn_mfma_f32_16x16x32_f16(
            af[mt], bf[nt], acc[mt][nt], 0, 0, 0);
    __syncthreads();
  }

  // ================= softmax over n (=Lq) per context row ================
  // C/D layout: col = l15, row = quad*4 + reg  [m89/m91]
#pragma unroll
  for (int mt = 0; mt < 4; ++mt)
#pragma unroll
    for (int r = 0; r < 4; ++r) {
      float m = fmaxf(fmaxf(acc[mt][0][r], acc[mt][1][r]),
                      fmaxf(acc[mt][2][r], acc[mt][3][r]));
      m = fmaxf(m, __shfl_xor(m, 1, 64));
      m = fmaxf(m, __shfl_xor(m, 2, 64));
      m = fmaxf(m, __shfl_xor(m, 4, 64));
      m = fmaxf(m, __shfl_xor(m, 8, 64));
      if (l15 == 0) redf[wave * 64 + mt * 16 + quad * 4 + r] = m;
    }
  __syncthreads();
  if (tid < 64) {
    float m = redf[tid];
#pragma unroll
    for (int w = 1; w < 8; ++w) m = fmaxf(m, redf[w * 64 + tid]);
    rowstat[tid] = m;
  }
  __syncthreads();
#pragma unroll
  for (int mt = 0; mt < 4; ++mt)
#pragma unroll
    for (int r = 0; r < 4; ++r) {
      const float m = rowstat[mt * 16 + quad * 4 + r];
      float s = 0.f;
#pragma unroll
      for (int nt = 0; nt < 4; ++nt) {
        const float e = __expf(acc[mt][nt][r] - m);
        acc[mt][nt][r] = e;
        s += e;
      }
      s += __shfl_xor(s, 1, 64);
      s += __shfl_xor(s, 2, 64);
      s += __shfl_xor(s, 4, 64);
      s += __shfl_xor(s, 8, 64);
      if (l15 == 0) redf[wave * 64 + mt * 16 + quad * 4 + r] = s;
    }
  __syncthreads();
  if (tid < 64) {
    float s = 0.f;
#pragma unroll
    for (int w = 0; w < 8; ++w) s += redf[w * 64 + tid];
    rowstat[tid] = 1.0f / s;
  }
  __syncthreads();
  // write P (fp16) to workspace — L2-resident, read back by this block only
#pragma unroll
  for (int mt = 0; mt < 4; ++mt)
#pragma unroll
    for (int r = 0; r < 4; ++r) {
      const float inv = rowstat[mt * 16 + quad * 4 + r];
      const size_t rowoff =
          (size_t)(c0 + mt * 16 + quad * 4 + r) * LQ + wave * 64 + l15;
#pragma unroll
      for (int nt = 0; nt < 4; ++nt)
        P[rowoff + nt * 16] = f2h(acc[mt][nt][r] * inv);
    }
  __syncthreads();   // drain P stores (vmcnt) before phase-2 re-read

  // ================= Phase 2: O = P (64x512) * Q (512x1024) ==============
#pragma unroll 1
  for (int nh = 0; nh < 2; ++nh) {
#pragma unroll
    for (int i = 0; i < 4; ++i)
#pragma unroll
      for (int j = 0; j < 4; ++j) acc[i][j] = floatx4{0.f, 0.f, 0.f, 0.f};
#pragma unroll 1
    for (int itq = 0; itq < 16; ++itq) {
      const int kq = itq * 32;
#pragma unroll
      for (int j = 0; j < 5; ++j) {
        const int bb = wave + j * 8;
        if (bb < 36) {
          const unsigned short* g;
          char* l;
          if (bb < 32) {    // QT frag block: rows = d index
            g = QT + (size_t)(nh * 512 + bb * 16 + l15) * LQ + kq + q8;
            l = Qbuf + bb * 1024;
          } else {          // P frag block: rows = context rows
            const int mt = bb - 32;
            g = P + (size_t)(c0 + mt * 16 + l15) * LQ + kq + q8;
            l = Cbuf + mt * 1024;
          }
          gl2lds16(g, l);
        }
      }
      __syncthreads();
      half8 af[4], bf[4];
#pragma unroll
      for (int mt = 0; mt < 4; ++mt)
        af[mt] = *(const half8*)(Cbuf + mt * 1024 + lane * 16);
#pragma unroll
      for (int nt = 0; nt < 4; ++nt)
        bf[nt] = *(const half8*)(Qbuf + (wave * 4 + nt) * 1024 + lane * 16);
#pragma unroll
      for (int mt = 0; mt < 4; ++mt)
#pragma unroll
        for (int nt = 0; nt < 4; ++nt)
          acc[mt][nt] = __builtin_amdgcn_mfma_f32_16x16x32_f16(
              af[mt], bf[nt], acc[mt][nt], 0, 0, 0);
      __syncthreads();
    }
    // epilogue: out[:, D + nh*512 + col] = O chunk (fp32)
#pragma unroll
    for (int mt = 0; mt < 4; ++mt)
#pragma unroll
      for (int r = 0; r < 4; ++r) {
        const size_t rowoff = (size_t)(c0 + mt * 16 + quad * 4 + r) * DO +
                              D_ + nh * 512 + wave * 64 + l15;
#pragma unroll
        for (int nt = 0; nt < 4; ++nt)
          O[rowoff + nt * 16] = acc[mt][nt][r];
      }
  }
}

extern "C" void kernel_launch(void* const* d_in, const int* in_sizes, int n_in,
                              void* d_out, int out_size, void* d_ws, size_t ws_size,
                              hipStream_t stream) {
  (void)in_sizes; (void)n_in; (void)out_size; (void)ws_size;
  const float* q = (const float*)d_in[0];
  const float* c = (const float*)d_in[1];
  float* out = (float*)d_out;
  // workspace layout (fp16 halves): Qh 16MiB | Ch 64MiB | QTh 16MiB | P 32MiB
  unsigned short* qh  = (unsigned short*)d_ws;
  unsigned short* ch  = qh  + (size_t)B_ * LQ * D_;
  unsigned short* qth = ch  + (size_t)B_ * LC * D_;
  unsigned short* p   = qth + (size_t)B_ * D_ * LQ;
  conv_kernel<<<1024, 256, 0, stream>>>(q, qh, (B_ * LQ * D_) / 4);
  conv_kernel<<<2048, 256, 0, stream>>>(c, ch, (B_ * LC * D_) / 4);
  qtransh_kernel<<<dim3(D_ / 32, LQ / 32, B_), dim3(32, 8), 0, stream>>>(qh, qth);
  attn_main<<<dim3(B_ * (LC / MT)), dim3(512), 0, stream>>>(qh, ch, qth, p, c, out);
}